// Round 2
// baseline (349.206 us; speedup 1.0000x reference)
//
#include <hip/hip_runtime.h>

// out[e] = concat(node_states[src[e]], node_states[tgt[e]])
// v3: same 8-edges-per-wave batched structure as v2, but PLAIN cached stores
// instead of nontemporal.
//
// A/B rationale: v2 sustained only ~2.6 TB/s effective while the harness's
// own fillBuffer kernel (plain stores) hits 6.3 TB/s on the same buffer.
// The NT path (L2 bypass) was inherited untested from a prior session; the
// node_states table is only 5 MB and L3-resident regardless, so even if the
// streaming output evicts it from L2, refetch cost is negligible.
//
// Per wave (64 lanes): lanes 0-31 = source half, lanes 32-63 = target half;
// one float4 per lane per edge; 8 consecutive edges per wave:
//   - 8 independent index loads issued together
//   - 8 independent gather loads issued together
//   - 8 stores (8 KB contiguous per wave)

typedef float v4f __attribute__((ext_vector_type(4)));

#define EPW 8  // edges per wave

__global__ __launch_bounds__(256) void NodePropagator_75110388073048_kernel(
    const v4f* __restrict__ ns,       // node_states as [N, 32] v4f
    const int* __restrict__ src32,    // edge_sources (int32 word view)
    const int* __restrict__ tgt32,    // edge_targets (int32 word view)
    v4f* __restrict__ out,            // [E, 64] v4f
    int nEdges)
{
    int tid  = blockIdx.x * blockDim.x + threadIdx.x;
    int wid  = tid >> 6;              // global wave id
    int lane = tid & 63;
    int half = lane >> 5;             // 0 = source half, 1 = target half
    int c    = lane & 31;             // v4f chunk within the half

    int e0 = wid * EPW;               // first edge this wave owns
    if (e0 >= nEdges) return;

    // --- index dtype probe (int64 vs int32), uniform, cached loads ---
    // Reference emits int64 (values < 10000 -> high words 0). For genuine
    // int32 data, 4 random values in [0,10000) all being 0 is ~1e-16.
    bool is_i64 = (src32[1] == 0) & (src32[3] == 0) &
                  (src32[5] == 0) & (src32[7] == 0);
    int stride = is_i64 ? 2 : 1;      // int32 words per index element

    const int* idxp = half ? tgt32 : src32;

    // Batch 1: independent index loads (low word of each index).
    int rows[EPW];
#pragma unroll
    for (int k = 0; k < EPW; ++k) {
        int e  = e0 + k;
        int ec = e < nEdges ? e : nEdges - 1;   // clamp, store guarded below
        rows[k] = idxp[ec * stride];
    }

    // Batch 2: independent gather loads (32 lanes x 16 B = 512 B contiguous
    // per half, per edge).
    v4f v[EPW];
#pragma unroll
    for (int k = 0; k < EPW; ++k)
        v[k] = ns[rows[k] * 32 + c];

    // Batch 3: plain cached stores (8 KB contiguous per wave).
#pragma unroll
    for (int k = 0; k < EPW; ++k) {
        int e = e0 + k;
        if (e < nEdges)
            out[e * 64 + lane] = v[k];
    }
}

extern "C" void kernel_launch(void* const* d_in, const int* in_sizes, int n_in,
                              void* d_out, int out_size, void* d_ws, size_t ws_size,
                              hipStream_t stream) {
    const v4f* ns  = (const v4f*)d_in[0];
    const int* src = (const int*)d_in[1];
    const int* tgt = (const int*)d_in[2];
    v4f*       out = (v4f*)d_out;

    int nEdges = in_sizes[1];                          // 320000
    long long waves   = ((long long)nEdges + EPW - 1) / EPW;
    long long threads = waves * 64;
    int block = 256;
    int grid  = (int)((threads + block - 1) / block);  // 10000 for E=320000

    NodePropagator_75110388073048_kernel<<<grid, block, 0, stream>>>(
        ns, src, tgt, out, nEdges);
}

// Round 4
// 342.120 us; speedup vs baseline: 1.0207x; 1.0207x over previous
//
#include <hip/hip_runtime.h>

// out[e] = concat(node_states[src[e]], node_states[tgt[e]])
// v4b: persistent waves + 2-stage software pipeline + NT stores.
// (Resubmission of v4 — previous round died on container acquisition, the
// kernel never ran.)
//
// A/B history: NT vs plain stores: NT wins (334 vs 349) -> NT kept.
// v2 (one-shot waves, MLP=8) sustained ~42% of the machine's demonstrated
// write BW. v4 makes waves persistent (grid-stride over 8-edge groups) and
// pipelines two groups: while group A's stores issue, group B's index loads
// and gathers are already in flight. Per-wave setup (dtype probe, address
// bases) and the end-of-wave NT-store drain are amortized over ~5 groups.
//
// Lanes 0-31 = source half, lanes 32-63 = target half; one float4 per lane
// per edge; EPW=8 edges per group (1 KB contiguous per edge per wave).

typedef float v4f __attribute__((ext_vector_type(4)));

#define EPW 8  // edges per group

__global__ __launch_bounds__(256) void NodePropagator_75110388073048_kernel(
    const v4f* __restrict__ ns,       // node_states as [N, 32] v4f
    const int* __restrict__ src32,    // edge_sources (int32 word view)
    const int* __restrict__ tgt32,    // edge_targets (int32 word view)
    v4f* __restrict__ out,            // [E, 64] v4f
    int nEdges, int nGroups, int totalWaves)
{
    int tid  = blockIdx.x * blockDim.x + threadIdx.x;
    int wid  = tid >> 6;              // global wave id
    int lane = tid & 63;
    int half = lane >> 5;             // 0 = source half, 1 = target half
    int c    = lane & 31;             // v4f chunk within the half

    // --- index dtype probe (int64 vs int32), uniform, cached loads ---
    // Reference emits int64 (values < 10000 -> high words 0). For genuine
    // int32 data, 4 random values in [0,10000) all being 0 is ~1e-16.
    bool is_i64 = (src32[1] == 0) & (src32[3] == 0) &
                  (src32[5] == 0) & (src32[7] == 0);
    int stride = is_i64 ? 2 : 1;      // int32 words per index element

    const int* idxp = half ? tgt32 : src32;

#define LOADIDX(g, rows)                                        \
    {                                                           \
        int base_ = (g) * EPW;                                  \
        _Pragma("unroll")                                       \
        for (int k = 0; k < EPW; ++k) {                         \
            int e_ = base_ + k;                                 \
            if (e_ >= nEdges) e_ = nEdges - 1;                  \
            rows[k] = idxp[e_ * stride];                        \
        }                                                       \
    }

#define GATHER(rows, v)                                         \
    {                                                           \
        _Pragma("unroll")                                       \
        for (int k = 0; k < EPW; ++k)                           \
            v[k] = ns[rows[k] * 32 + c];                        \
    }

#define STORE(v, g)                                             \
    {                                                           \
        int base_ = (g) * EPW;                                  \
        _Pragma("unroll")                                       \
        for (int k = 0; k < EPW; ++k) {                         \
            int e_ = base_ + k;                                 \
            if (e_ < nEdges)                                    \
                __builtin_nontemporal_store(v[k],               \
                    &out[e_ * 64 + lane]);                      \
        }                                                       \
    }

    int gA = wid;
    if (gA >= nGroups) return;

    int rA[EPW]; v4f vA[EPW];
    int rB[EPW]; v4f vB[EPW];

    LOADIDX(gA, rA);
    GATHER(rA, vA);

    // 2-stage pipeline; A/B roles alternate via duplicated body so all array
    // indexing stays compile-time (no scratch spills).
    while (true) {
        int gB = gA + totalWaves;
        bool hB = gB < nGroups;
        if (hB) { LOADIDX(gB, rB); GATHER(rB, vB); }  // in flight during A's stores
        STORE(vA, gA);
        if (!hB) return;

        int gC = gB + totalWaves;
        bool hC = gC < nGroups;
        if (hC) { LOADIDX(gC, rA); GATHER(rA, vA); }  // in flight during B's stores
        STORE(vB, gB);
        if (!hC) return;
        gA = gC;
    }
}

extern "C" void kernel_launch(void* const* d_in, const int* in_sizes, int n_in,
                              void* d_out, int out_size, void* d_ws, size_t ws_size,
                              hipStream_t stream) {
    const v4f* ns  = (const v4f*)d_in[0];
    const int* src = (const int*)d_in[1];
    const int* tgt = (const int*)d_in[2];
    v4f*       out = (v4f*)d_out;

    int nEdges  = in_sizes[1];                         // 320000
    int nGroups = (nEdges + EPW - 1) / EPW;            // 40000

    int block = 256;                                   // 4 waves/block
    int grid  = 2048;                                  // 8 blocks/CU worth of waves
    int totalWaves = grid * (block / 64);              // 8192
    if (totalWaves > nGroups) {
        totalWaves = nGroups;
        grid = (totalWaves + (block / 64) - 1) / (block / 64);
    }

    NodePropagator_75110388073048_kernel<<<grid, block, 0, stream>>>(
        ns, src, tgt, out, nEdges, nGroups, totalWaves);
}

// Round 5
// 333.786 us; speedup vs baseline: 1.0462x; 1.0250x over previous
//
#include <hip/hip_runtime.h>

// out[e] = concat(node_states[src[e]], node_states[tgt[e]])
// v5: one-shot waves (v2 structure, the A/B winner) + scalar-path index
// loads + EPW=16.
//
// A/B history:
//   v1 (no MLP)            kernel ~155 us
//   v2 (EPW=8, NT stores)  kernel ~125 us   <- best
//   v3 (plain stores)      kernel ~140 us   (L2 pollution of the table)
//   v4 (2-stage pipeline)  kernel ~137 us   (in-order vmcnt: load-waits sit
//                                            behind NT stores; WAR on store
//                                            data regs pins loop to store ack)
// Lesson: scheduling variants cluster at 125-140 -> attack the per-wave
// fixed costs instead.
//
// v5 changes:
//  - wave id forced uniform via readfirstlane so ALL index addresses are
//    provably wave-uniform -> compiler can use scalar loads (SMEM/lgkmcnt),
//    taking the index fetch out of the in-order vmcnt stream shared with
//    gathers/NT stores. Both src and tgt rows are loaded; per-lane half
//    select is one cndmask.
//  - EPW 16: halves wave count, doubles gather MLP, amortizes probe/setup/
//    NT-drain over 16 KB of output per wave.
//
// Lanes 0-31 = source half, lanes 32-63 = target half; one float4 per lane
// per edge (wave writes 1 KB contiguous per edge).

typedef float v4f __attribute__((ext_vector_type(4)));

#define EPW 16  // edges per wave

__global__ __launch_bounds__(256) void NodePropagator_75110388073048_kernel(
    const v4f* __restrict__ ns,       // node_states as [N, 32] v4f
    const int* __restrict__ src32,    // edge_sources (int32 word view)
    const int* __restrict__ tgt32,    // edge_targets (int32 word view)
    v4f* __restrict__ out,            // [E, 64] v4f
    int nEdges)
{
    int lane  = threadIdx.x & 63;
    // Force the wave id into an SGPR so index addresses are wave-uniform.
    int wslot = __builtin_amdgcn_readfirstlane(threadIdx.x >> 6);
    int wid   = blockIdx.x * (256 / 64) + wslot;
    int e0    = wid * EPW;
    if (e0 >= nEdges) return;

    int half = lane >> 5;             // 0 = source half, 1 = target half
    int c    = lane & 31;             // v4f chunk within the half

    // --- index dtype probe (int64 vs int32), uniform loads ---
    // Reference emits int64 (values < 10000 -> high words 0). For genuine
    // int32 data, 4 random values in [0,10000) all being 0 is ~1e-16.
    bool is_i64 = (src32[1] == 0) & (src32[3] == 0) &
                  (src32[5] == 0) & (src32[7] == 0);

    // Load BOTH src and tgt row indices for all EPW edges (uniform scalar
    // values), then select per lane-half.
    int srow[EPW], trow[EPW];
    if (is_i64) {
        const long long* s64 = (const long long*)src32;
        const long long* t64 = (const long long*)tgt32;
#pragma unroll
        for (int k = 0; k < EPW; ++k) {
            int e = e0 + k;
            if (e >= nEdges) e = nEdges - 1;
            srow[k] = (int)s64[e];
            trow[k] = (int)t64[e];
        }
    } else {
#pragma unroll
        for (int k = 0; k < EPW; ++k) {
            int e = e0 + k;
            if (e >= nEdges) e = nEdges - 1;
            srow[k] = src32[e];
            trow[k] = tgt32[e];
        }
    }

    // Batched independent gathers: 16 outstanding, 2 rows x 512 B contiguous
    // per edge per wave.
    v4f v[EPW];
#pragma unroll
    for (int k = 0; k < EPW; ++k) {
        int row = half ? trow[k] : srow[k];
        v[k] = ns[row * 32 + c];
    }

    // NT streaming stores: 16 KB contiguous per wave; bypasses L2 so the
    // 5 MB node_states table stays cached for the gathers.
#pragma unroll
    for (int k = 0; k < EPW; ++k) {
        int e = e0 + k;
        if (e < nEdges)
            __builtin_nontemporal_store(v[k], &out[e * 64 + lane]);
    }
}

extern "C" void kernel_launch(void* const* d_in, const int* in_sizes, int n_in,
                              void* d_out, int out_size, void* d_ws, size_t ws_size,
                              hipStream_t stream) {
    const v4f* ns  = (const v4f*)d_in[0];
    const int* src = (const int*)d_in[1];
    const int* tgt = (const int*)d_in[2];
    v4f*       out = (v4f*)d_out;

    int nEdges = in_sizes[1];                          // 320000
    long long waves   = ((long long)nEdges + EPW - 1) / EPW;   // 20000
    long long threads = waves * 64;
    int block = 256;
    int grid  = (int)((threads + block - 1) / block);  // 5000

    NodePropagator_75110388073048_kernel<<<grid, block, 0, stream>>>(
        ns, src, tgt, out, nEdges);
}